// Round 2
// baseline (181.611 us; speedup 1.0000x reference)
//
#include <hip/hip_runtime.h>

#define NN 100000
#define NE 500000
#define FEAT 128
#define CHN 128
#define K2 256

#define IDX_OFF 12800000
#define EDGE_OUT_OFF 13800000
#define U_OFF 77800000

typedef short bf8 __attribute__((ext_vector_type(8)));
typedef float f32x4 __attribute__((ext_vector_type(4)));

__device__ __forceinline__ unsigned short f2bf(float x) {
    union { float f; unsigned u; } v; v.f = x;
    return (unsigned short)((v.u + 0x7fffu + ((v.u >> 16) & 1u)) >> 16);
}

__device__ __forceinline__ bf8 pack8(const float4 x0, const float4 x1) {
    bf8 r;
    r[0] = (short)f2bf(x0.x); r[1] = (short)f2bf(x0.y);
    r[2] = (short)f2bf(x0.z); r[3] = (short)f2bf(x0.w);
    r[4] = (short)f2bf(x1.x); r[5] = (short)f2bf(x1.y);
    r[6] = (short)f2bf(x1.z); r[7] = (short)f2bf(x1.w);
    return r;
}

// ---------------- node projection: out[m][c] = sum_k nf[m][k]*W[c][k] + b[c]
__global__ __launch_bounds__(256) void node_gemm(const float* __restrict__ nf,
                                                 const float* __restrict__ W,
                                                 const float* __restrict__ bias,
                                                 float* __restrict__ out) {
    __shared__ __align__(16) unsigned short Wl[CHN][FEAT + 8];   // bf16, padded
    const int tid = threadIdx.x;
    // stage W (128x128 f32 -> bf16 LDS)
    for (int i = tid * 4; i < CHN * FEAT; i += 256 * 4) {
        const float4 w = *(const float4*)(W + i);
        const int r = i >> 7, c = i & 127;
        unsigned short* p = &Wl[r][c];
        p[0] = f2bf(w.x); p[1] = f2bf(w.y); p[2] = f2bf(w.z); p[3] = f2bf(w.w);
    }
    __syncthreads();

    const int wv = tid >> 6;
    const int l = tid & 63;
    const int l15 = l & 15, lq = l >> 4;
    const int rowblk = blockIdx.x * 128 + wv * 32;
    if (rowblk >= NN) return;            // NN % 32 == 0 -> both subtiles valid

    f32x4 acc[2][8];
    for (int s = 0; s < 2; ++s)
        for (int n = 0; n < 8; ++n)
            acc[s][n] = (f32x4){0.f, 0.f, 0.f, 0.f};

    const int kl = lq * 8;
#pragma unroll
    for (int t = 0; t < 4; ++t) {
        const int kb = t * 32 + kl;
        bf8 a[2];
#pragma unroll
        for (int s = 0; s < 2; ++s) {
            const float* ap = nf + (size_t)(rowblk + s * 16 + l15) * FEAT + kb;
            a[s] = pack8(*(const float4*)ap, *(const float4*)(ap + 4));
        }
#pragma unroll
        for (int n = 0; n < 8; ++n) {
            const bf8 bfr = *(const bf8*)&Wl[n * 16 + l15][kb];
            acc[0][n] = __builtin_amdgcn_mfma_f32_16x16x32_bf16(a[0], bfr, acc[0][n], 0, 0, 0);
            acc[1][n] = __builtin_amdgcn_mfma_f32_16x16x32_bf16(a[1], bfr, acc[1][n], 0, 0, 0);
        }
    }

    for (int s = 0; s < 2; ++s) {
        const int m0 = rowblk + s * 16 + lq * 4;
#pragma unroll
        for (int n = 0; n < 8; ++n) {
            const int c = n * 16 + l15;
            const float bv = bias[c];
#pragma unroll
            for (int i = 0; i < 4; ++i)
                out[(size_t)(m0 + i) * CHN + c] = acc[s][n][i] + bv;
        }
    }
}

// ---------------- edge GEMM: edge_in[e] = concat(nf[src[e]], nf[dst[e]])
__global__ __launch_bounds__(256) void edge_gemm(const float* __restrict__ nf,
                                                 const int* __restrict__ eidx,
                                                 const float* __restrict__ W,
                                                 const float* __restrict__ bias,
                                                 float* __restrict__ out) {
    __shared__ __align__(16) unsigned short Wl[CHN][K2 + 8];     // 128x264 bf16 = 66 KB
    const int tid = threadIdx.x;
    for (int i = tid * 4; i < CHN * K2; i += 256 * 4) {
        const float4 w = *(const float4*)(W + i);
        const int r = i >> 8, c = i & 255;
        unsigned short* p = &Wl[r][c];
        p[0] = f2bf(w.x); p[1] = f2bf(w.y); p[2] = f2bf(w.z); p[3] = f2bf(w.w);
    }
    __syncthreads();

    const int wv = tid >> 6;
    const int l = tid & 63;
    const int l15 = l & 15, lq = l >> 4;
    const int rowblk = blockIdx.x * 128 + wv * 32;
    if (rowblk >= NE) return;            // NE % 32 == 0

    // per-lane edge endpoints for the two 16-edge subtiles
    const int e0 = rowblk + l15;
    const int e1 = rowblk + 16 + l15;
    const int s00 = eidx[e0],      s01 = eidx[e1];        // src row
    const int s10 = eidx[NE + e0], s11 = eidx[NE + e1];   // dst row

    f32x4 acc[2][8];
    for (int s = 0; s < 2; ++s)
        for (int n = 0; n < 8; ++n)
            acc[s][n] = (f32x4){0.f, 0.f, 0.f, 0.f};

    const int kl = lq * 8;
#pragma unroll
    for (int t = 0; t < 8; ++t) {
        const int kb = t * 32 + kl;        // 0..255
        const int col = kb & 127;          // kb>=128 <=> t>=4 (uniform)
        const int r0 = (t < 4) ? s00 : s10;
        const int r1 = (t < 4) ? s01 : s11;
        const float* ap0 = nf + (size_t)r0 * FEAT + col;
        const float* ap1 = nf + (size_t)r1 * FEAT + col;
        bf8 a0 = pack8(*(const float4*)ap0, *(const float4*)(ap0 + 4));
        bf8 a1 = pack8(*(const float4*)ap1, *(const float4*)(ap1 + 4));
#pragma unroll
        for (int n = 0; n < 8; ++n) {
            const bf8 bfr = *(const bf8*)&Wl[n * 16 + l15][kb];
            acc[0][n] = __builtin_amdgcn_mfma_f32_16x16x32_bf16(a0, bfr, acc[0][n], 0, 0, 0);
            acc[1][n] = __builtin_amdgcn_mfma_f32_16x16x32_bf16(a1, bfr, acc[1][n], 0, 0, 0);
        }
    }

    for (int s = 0; s < 2; ++s) {
        const int m0 = rowblk + s * 16 + lq * 4;
#pragma unroll
        for (int n = 0; n < 8; ++n) {
            const int c = n * 16 + l15;
            const float bv = bias[c];
#pragma unroll
            for (int i = 0; i < 4; ++i)
                out[(size_t)(m0 + i) * CHN + c] = acc[s][n][i] + bv;
        }
    }
}

// ---------------- passthroughs: edge_indexes as f32, u_features
__global__ __launch_bounds__(256) void misc_copy(const int* __restrict__ eidx,
                                                 const float* __restrict__ u,
                                                 float* __restrict__ out) {
    const unsigned i = blockIdx.x * 256 + threadIdx.x;
    if (i < 2u * NE) out[IDX_OFF + (size_t)i] = (float)eidx[i];
    if (i < CHN) out[U_OFF + (size_t)i] = u[i];
}

extern "C" void kernel_launch(void* const* d_in, const int* in_sizes, int n_in,
                              void* d_out, int out_size, void* d_ws, size_t ws_size,
                              hipStream_t stream) {
    const float* nf   = (const float*)d_in[0];
    const int*   eidx = (const int*)d_in[1];
    const float* u    = (const float*)d_in[3];
    const float* nW   = (const float*)d_in[4];
    const float* nb   = (const float*)d_in[5];
    const float* eW   = (const float*)d_in[6];
    const float* eb   = (const float*)d_in[7];
    float* out = (float*)d_out;

    hipLaunchKernelGGL(node_gemm, dim3((NN + 127) / 128), dim3(256), 0, stream,
                       nf, nW, nb, out);
    hipLaunchKernelGGL(edge_gemm, dim3((NE + 127) / 128), dim3(256), 0, stream,
                       nf, eidx, eW, eb, out + EDGE_OUT_OFF);
    hipLaunchKernelGGL(misc_copy, dim3((2 * NE + 255) / 256), dim3(256), 0, stream,
                       eidx, u, out);
}

// Round 3
// 180.495 us; speedup vs baseline: 1.0062x; 1.0062x over previous
//
#include <hip/hip_runtime.h>

#define NN 100000
#define NE 500000
#define FEAT 128
#define CHN 128
#define K2 256

#define IDX_OFF 12800000
#define EDGE_OUT_OFF 13800000
#define U_OFF 77800000

typedef short bf8 __attribute__((ext_vector_type(8)));
typedef float f32x4 __attribute__((ext_vector_type(4)));

__device__ __forceinline__ unsigned short f2bf(float x) {
    union { float f; unsigned u; } v; v.f = x;
    return (unsigned short)((v.u + 0x7fffu + ((v.u >> 16) & 1u)) >> 16);
}

__device__ __forceinline__ bf8 pack8(const float4 x0, const float4 x1) {
    bf8 r;
    r[0] = (short)f2bf(x0.x); r[1] = (short)f2bf(x0.y);
    r[2] = (short)f2bf(x0.z); r[3] = (short)f2bf(x0.w);
    r[4] = (short)f2bf(x1.x); r[5] = (short)f2bf(x1.y);
    r[6] = (short)f2bf(x1.z); r[7] = (short)f2bf(x1.w);
    return r;
}

// ---------------- node projection + fused nf->bf16 materialization
__global__ __launch_bounds__(256) void node_gemm(const float* __restrict__ nf,
                                                 const float* __restrict__ W,
                                                 const float* __restrict__ bias,
                                                 float* __restrict__ out,
                                                 unsigned short* __restrict__ nf16) {
    __shared__ __align__(16) unsigned short Wl[CHN][FEAT + 8];
    const int tid = threadIdx.x;
    for (int i = tid * 4; i < CHN * FEAT; i += 256 * 4) {
        const float4 w = *(const float4*)(W + i);
        const int r = i >> 7, c = i & 127;
        unsigned short* p = &Wl[r][c];
        p[0] = f2bf(w.x); p[1] = f2bf(w.y); p[2] = f2bf(w.z); p[3] = f2bf(w.w);
    }
    __syncthreads();

    const int wv = tid >> 6;
    const int l = tid & 63;
    const int l15 = l & 15, lq = l >> 4;
    const int rowblk = blockIdx.x * 128 + wv * 32;
    if (rowblk >= NN) return;            // NN % 32 == 0 -> both subtiles valid

    f32x4 acc[2][8];
    for (int s = 0; s < 2; ++s)
        for (int n = 0; n < 8; ++n)
            acc[s][n] = (f32x4){0.f, 0.f, 0.f, 0.f};

    const int kl = lq * 8;
#pragma unroll
    for (int t = 0; t < 4; ++t) {
        const int kb = t * 32 + kl;
        bf8 a[2];
#pragma unroll
        for (int s = 0; s < 2; ++s) {
            const int row = rowblk + s * 16 + l15;
            const float* ap = nf + (size_t)row * FEAT + kb;
            a[s] = pack8(*(const float4*)ap, *(const float4*)(ap + 4));
            if (nf16) *(bf8*)(nf16 + (size_t)row * FEAT + kb) = a[s];
        }
#pragma unroll
        for (int n = 0; n < 8; ++n) {
            const bf8 bfr = *(const bf8*)&Wl[n * 16 + l15][kb];
            acc[0][n] = __builtin_amdgcn_mfma_f32_16x16x32_bf16(a[0], bfr, acc[0][n], 0, 0, 0);
            acc[1][n] = __builtin_amdgcn_mfma_f32_16x16x32_bf16(a[1], bfr, acc[1][n], 0, 0, 0);
        }
    }

    for (int s = 0; s < 2; ++s) {
        const int m0 = rowblk + s * 16 + lq * 4;
#pragma unroll
        for (int n = 0; n < 8; ++n) {
            const int c = n * 16 + l15;
            const float bv = bias[c];
#pragma unroll
            for (int i = 0; i < 4; ++i)
                out[(size_t)(m0 + i) * CHN + c] = acc[s][n][i] + bv;
        }
    }
}

// ---------------- edge GEMM, bf16 gather path (M_rep=4: 64 edges/wave)
__global__ __launch_bounds__(256) void edge_gemm_bf(const unsigned short* __restrict__ nf16,
                                                    const int* __restrict__ eidx,
                                                    const float* __restrict__ W,
                                                    const float* __restrict__ bias,
                                                    float* __restrict__ out) {
    __shared__ __align__(16) unsigned short Wl[CHN][K2 + 8];     // 66 KB
    const int tid = threadIdx.x;
    for (int i = tid * 4; i < CHN * K2; i += 256 * 4) {
        const float4 w = *(const float4*)(W + i);
        const int r = i >> 8, c = i & 255;
        unsigned short* p = &Wl[r][c];
        p[0] = f2bf(w.x); p[1] = f2bf(w.y); p[2] = f2bf(w.z); p[3] = f2bf(w.w);
    }
    __syncthreads();

    const int wv = tid >> 6;
    const int l = tid & 63;
    const int l15 = l & 15, lq = l >> 4;
    const int rowblk = blockIdx.x * 256 + wv * 64;
    if (rowblk >= NE) return;

    int srcr[4], dstr[4];
    bool val[4];
#pragma unroll
    for (int s = 0; s < 4; ++s) {
        val[s] = (rowblk + s * 16) < NE;          // NE % 16 == 0 -> all-or-nothing per subtile
        const int e = rowblk + s * 16 + l15;
        srcr[s] = val[s] ? eidx[e] : 0;
        dstr[s] = val[s] ? eidx[NE + e] : 0;
    }

    f32x4 acc[4][8];
    for (int s = 0; s < 4; ++s)
        for (int n = 0; n < 8; ++n)
            acc[s][n] = (f32x4){0.f, 0.f, 0.f, 0.f};

    const int kl = lq * 8;
#pragma unroll
    for (int t = 0; t < 8; ++t) {
        const int kb = t * 32 + kl;        // 0..255
        const int col = kb & 127;
        bf8 a[4];
#pragma unroll
        for (int s = 0; s < 4; ++s) {
            const int r = (t < 4) ? srcr[s] : dstr[s];
            a[s] = *(const bf8*)(nf16 + (size_t)r * FEAT + col);
        }
#pragma unroll
        for (int n = 0; n < 8; ++n) {
            const bf8 bfr = *(const bf8*)&Wl[n * 16 + l15][kb];
#pragma unroll
            for (int s = 0; s < 4; ++s)
                acc[s][n] = __builtin_amdgcn_mfma_f32_16x16x32_bf16(a[s], bfr, acc[s][n], 0, 0, 0);
        }
    }

    for (int s = 0; s < 4; ++s) {
        if (!val[s]) continue;
        const int m0 = rowblk + s * 16 + lq * 4;
#pragma unroll
        for (int n = 0; n < 8; ++n) {
            const int c = n * 16 + l15;
            const float bv = bias[c];
#pragma unroll
            for (int i = 0; i < 4; ++i)
                out[(size_t)(m0 + i) * CHN + c] = acc[s][n][i] + bv;
        }
    }
}

// ---------------- edge GEMM, f32 fallback (no workspace)
__global__ __launch_bounds__(256) void edge_gemm_f32(const float* __restrict__ nf,
                                                     const int* __restrict__ eidx,
                                                     const float* __restrict__ W,
                                                     const float* __restrict__ bias,
                                                     float* __restrict__ out) {
    __shared__ __align__(16) unsigned short Wl[CHN][K2 + 8];
    const int tid = threadIdx.x;
    for (int i = tid * 4; i < CHN * K2; i += 256 * 4) {
        const float4 w = *(const float4*)(W + i);
        const int r = i >> 8, c = i & 255;
        unsigned short* p = &Wl[r][c];
        p[0] = f2bf(w.x); p[1] = f2bf(w.y); p[2] = f2bf(w.z); p[3] = f2bf(w.w);
    }
    __syncthreads();

    const int wv = tid >> 6;
    const int l = tid & 63;
    const int l15 = l & 15, lq = l >> 4;
    const int rowblk = blockIdx.x * 128 + wv * 32;
    if (rowblk >= NE) return;

    const int e0 = rowblk + l15;
    const int e1 = rowblk + 16 + l15;
    const int s00 = eidx[e0],      s01 = eidx[e1];
    const int s10 = eidx[NE + e0], s11 = eidx[NE + e1];

    f32x4 acc[2][8];
    for (int s = 0; s < 2; ++s)
        for (int n = 0; n < 8; ++n)
            acc[s][n] = (f32x4){0.f, 0.f, 0.f, 0.f};

    const int kl = lq * 8;
#pragma unroll
    for (int t = 0; t < 8; ++t) {
        const int kb = t * 32 + kl;
        const int col = kb & 127;
        const int r0 = (t < 4) ? s00 : s10;
        const int r1 = (t < 4) ? s01 : s11;
        const float* ap0 = nf + (size_t)r0 * FEAT + col;
        const float* ap1 = nf + (size_t)r1 * FEAT + col;
        bf8 a0 = pack8(*(const float4*)ap0, *(const float4*)(ap0 + 4));
        bf8 a1 = pack8(*(const float4*)ap1, *(const float4*)(ap1 + 4));
#pragma unroll
        for (int n = 0; n < 8; ++n) {
            const bf8 bfr = *(const bf8*)&Wl[n * 16 + l15][kb];
            acc[0][n] = __builtin_amdgcn_mfma_f32_16x16x32_bf16(a0, bfr, acc[0][n], 0, 0, 0);
            acc[1][n] = __builtin_amdgcn_mfma_f32_16x16x32_bf16(a1, bfr, acc[1][n], 0, 0, 0);
        }
    }

    for (int s = 0; s < 2; ++s) {
        const int m0 = rowblk + s * 16 + lq * 4;
#pragma unroll
        for (int n = 0; n < 8; ++n) {
            const int c = n * 16 + l15;
            const float bv = bias[c];
#pragma unroll
            for (int i = 0; i < 4; ++i)
                out[(size_t)(m0 + i) * CHN + c] = acc[s][n][i] + bv;
        }
    }
}

// ---------------- passthroughs: edge_indexes as f32, u_features
__global__ __launch_bounds__(256) void misc_copy(const int* __restrict__ eidx,
                                                 const float* __restrict__ u,
                                                 float* __restrict__ out) {
    const unsigned i = blockIdx.x * 256 + threadIdx.x;
    if (i < 2u * NE) out[IDX_OFF + (size_t)i] = (float)eidx[i];
    if (i < CHN) out[U_OFF + (size_t)i] = u[i];
}

extern "C" void kernel_launch(void* const* d_in, const int* in_sizes, int n_in,
                              void* d_out, int out_size, void* d_ws, size_t ws_size,
                              hipStream_t stream) {
    const float* nf   = (const float*)d_in[0];
    const int*   eidx = (const int*)d_in[1];
    const float* u    = (const float*)d_in[3];
    const float* nW   = (const float*)d_in[4];
    const float* nb   = (const float*)d_in[5];
    const float* eW   = (const float*)d_in[6];
    const float* eb   = (const float*)d_in[7];
    float* out = (float*)d_out;

    const bool useWs = ws_size >= (size_t)NN * FEAT * sizeof(unsigned short);
    unsigned short* nf16 = useWs ? (unsigned short*)d_ws : nullptr;

    hipLaunchKernelGGL(node_gemm, dim3((NN + 127) / 128), dim3(256), 0, stream,
                       nf, nW, nb, out, nf16);
    if (useWs) {
        hipLaunchKernelGGL(edge_gemm_bf, dim3((NE + 255) / 256), dim3(256), 0, stream,
                           nf16, eidx, eW, eb, out + EDGE_OUT_OFF);
    } else {
        hipLaunchKernelGGL(edge_gemm_f32, dim3((NE + 127) / 128), dim3(256), 0, stream,
                           nf, eidx, eW, eb, out + EDGE_OUT_OFF);
    }
    hipLaunchKernelGGL(misc_copy, dim3((2 * NE + 255) / 256), dim3(256), 0, stream,
                       eidx, u, out);
}

// Round 5
// 172.436 us; speedup vs baseline: 1.0532x; 1.0467x over previous
//
#include <hip/hip_runtime.h>
#include <hip/hip_bf16.h>

#define NN 100000
#define NE 500000
#define FEAT 128
#define CHN 128

#define IDX_OFF 12800000
#define EDGE_OUT_OFF 13800000
#define U_OFF 77800000

#define EBLK_CNT 358
#define NBLK_CNT 154
#define GRID (EBLK_CNT + NBLK_CNT)
#define ETILES 1954          // ceil(NE/256)
#define NTILES 782           // ceil(NN/128)

#define EW_STRIDE 264        // 256 + 8 pad (bf16 elems)
#define NW_STRIDE 136        // 128 + 8 pad

typedef short bf8 __attribute__((ext_vector_type(8)));
typedef float f32x4 __attribute__((ext_vector_type(4)));

__device__ __forceinline__ unsigned cvt2(float lo, float hi) {
    __hip_bfloat162 h = __float22bfloat162_rn(make_float2(lo, hi));
    union { __hip_bfloat162 h; unsigned u; } v; v.h = h;
    return v.u;
}

__device__ __forceinline__ bf8 pack8(const float4 a, const float4 b) {
    union { bf8 v; unsigned u[4]; } r;
    r.u[0] = cvt2(a.x, a.y); r.u[1] = cvt2(a.z, a.w);
    r.u[2] = cvt2(b.x, b.y); r.u[3] = cvt2(b.z, b.w);
    return r.v;
}

__global__ __launch_bounds__(256) void fused_all(
        const float* __restrict__ nf, const int* __restrict__ eidx,
        const float* __restrict__ u,
        const float* __restrict__ nW, const float* __restrict__ nbias,
        const float* __restrict__ eW, const float* __restrict__ ebias,
        float* __restrict__ out) {
    __shared__ __align__(16) unsigned short Wl[128 * EW_STRIDE];   // 66 KB, reused by both roles
    const int tid = threadIdx.x;
    const int wv = tid >> 6, l = tid & 63, l15 = l & 15, lq = l >> 4;
    const int kl = lq * 8;
    const int bid = blockIdx.x;

    if (bid < EBLK_CNT) {
        // ================= edge role =================
        for (int i = tid * 4; i < CHN * 256; i += 256 * 4) {
            const float4 w = *(const float4*)(eW + i);
            unsigned short* p = &Wl[(i >> 8) * EW_STRIDE + (i & 255)];
            *(unsigned*)&p[0] = cvt2(w.x, w.y);
            *(unsigned*)&p[2] = cvt2(w.z, w.w);
        }
        __syncthreads();
        float bv[8];
#pragma unroll
        for (int n = 0; n < 8; ++n) bv[n] = ebias[n * 16 + l15];
        float* oute = out + EDGE_OUT_OFF;

        for (int tile = bid; tile < ETILES; tile += EBLK_CNT) {
            const int rowblk = tile * 256 + wv * 64;
            if (rowblk >= NE) continue;
            int rs[4], rd[4]; bool val[4];
#pragma unroll
            for (int s = 0; s < 4; ++s) {
                val[s] = rowblk + s * 16 < NE;     // NE % 16 == 0: all-or-nothing
                const int e = rowblk + s * 16 + l15;
                rs[s] = val[s] ? eidx[e] : 0;
                rd[s] = val[s] ? eidx[NE + e] : 0;
            }
            f32x4 acc[4][8];
            for (int s = 0; s < 4; ++s)
                for (int n = 0; n < 8; ++n) acc[s][n] = (f32x4){0.f, 0.f, 0.f, 0.f};
#pragma unroll
            for (int t = 0; t < 8; ++t) {
                const int kb = t * 32 + kl;        // 0..255
                const int col = kb & 127;          // t>=4 -> dst half, uniform
                bf8 a[4];
#pragma unroll
                for (int s = 0; s < 4; ++s) {
                    const float* ap = nf + (size_t)((t < 4) ? rs[s] : rd[s]) * FEAT + col;
                    a[s] = pack8(*(const float4*)ap, *(const float4*)(ap + 4));
                }
#pragma unroll
                for (int n = 0; n < 8; ++n) {
                    const bf8 wf = *(const bf8*)&Wl[(n * 16 + l15) * EW_STRIDE + kb];
#pragma unroll
                    for (int s = 0; s < 4; ++s)
                        acc[s][n] = __builtin_amdgcn_mfma_f32_16x16x32_bf16(a[s], wf, acc[s][n], 0, 0, 0);
                }
            }
#pragma unroll
            for (int s = 0; s < 4; ++s) {
                if (!val[s]) continue;
                const int m0 = rowblk + s * 16 + lq * 4;
#pragma unroll
                for (int n = 0; n < 8; ++n)
#pragma unroll
                    for (int i = 0; i < 4; ++i)
                        oute[(size_t)(m0 + i) * CHN + n * 16 + l15] = acc[s][n][i] + bv[n];
            }
        }
    } else {
        // ================= node role + misc =================
        const int rb = bid - EBLK_CNT;
        for (int i = tid * 4; i < CHN * FEAT; i += 256 * 4) {
            const float4 w = *(const float4*)(nW + i);
            unsigned short* p = &Wl[(i >> 7) * NW_STRIDE + (i & 127)];
            *(unsigned*)&p[0] = cvt2(w.x, w.y);
            *(unsigned*)&p[2] = cvt2(w.z, w.w);
        }
        __syncthreads();
        float bv[8];
#pragma unroll
        for (int n = 0; n < 8; ++n) bv[n] = nbias[n * 16 + l15];

        for (int tile = rb; tile < NTILES; tile += NBLK_CNT) {
            const int rowblk = tile * 128 + wv * 32;
            if (rowblk >= NN) continue;            // NN % 32 == 0: full subtiles
            f32x4 acc[2][8];
            for (int s = 0; s < 2; ++s)
                for (int n = 0; n < 8; ++n) acc[s][n] = (f32x4){0.f, 0.f, 0.f, 0.f};
#pragma unroll
            for (int t = 0; t < 4; ++t) {
                const int kb = t * 32 + kl;
                bf8 a[2];
#pragma unroll
                for (int s = 0; s < 2; ++s) {
                    const float* ap = nf + (size_t)(rowblk + s * 16 + l15) * FEAT + kb;
                    a[s] = pack8(*(const float4*)ap, *(const float4*)(ap + 4));
                }
#pragma unroll
                for (int n = 0; n < 8; ++n) {
                    const bf8 wf = *(const bf8*)&Wl[(n * 16 + l15) * NW_STRIDE + kb];
                    acc[0][n] = __builtin_amdgcn_mfma_f32_16x16x32_bf16(a[0], wf, acc[0][n], 0, 0, 0);
                    acc[1][n] = __builtin_amdgcn_mfma_f32_16x16x32_bf16(a[1], wf, acc[1][n], 0, 0, 0);
                }
            }
#pragma unroll
            for (int s = 0; s < 2; ++s) {
                const int m0 = rowblk + s * 16 + lq * 4;
#pragma unroll
                for (int n = 0; n < 8; ++n)
#pragma unroll
                    for (int i = 0; i < 4; ++i)
                        out[(size_t)(m0 + i) * CHN + n * 16 + l15] = acc[s][n][i] + bv[n];
            }
        }

        // misc: edge_indexes -> f32, u passthrough
        const int4* ei4 = (const int4*)eidx;
        float4* oi4 = (float4*)(out + IDX_OFF);
        for (int i = rb * 256 + tid; i < (2 * NE) / 4; i += NBLK_CNT * 256) {
            const int4 v = ei4[i];
            oi4[i] = make_float4((float)v.x, (float)v.y, (float)v.z, (float)v.w);
        }
        if (rb == 0 && tid < CHN) out[U_OFF + tid] = u[tid];
    }
}

extern "C" void kernel_launch(void* const* d_in, const int* in_sizes, int n_in,
                              void* d_out, int out_size, void* d_ws, size_t ws_size,
                              hipStream_t stream) {
    const float* nf   = (const float*)d_in[0];
    const int*   eidx = (const int*)d_in[1];
    const float* u    = (const float*)d_in[3];
    const float* nW   = (const float*)d_in[4];
    const float* nb   = (const float*)d_in[5];
    const float* eW   = (const float*)d_in[6];
    const float* eb   = (const float*)d_in[7];
    float* out = (float*)d_out;

    hipLaunchKernelGGL(fused_all, dim3(GRID), dim3(256), 0, stream,
                       nf, eidx, u, nW, nb, eW, eb, out);
}